// Round 2
// baseline (1424.794 us; speedup 1.0000x reference)
//
#include <hip/hip_runtime.h>
#include <hip/hip_bf16.h>

typedef __hip_bfloat16 bf16;

#define BIG 100000.0f

// ---------------------------------------------------------------------------
// conv 3x3 SAME, Cin=64, Cout=64, + bias + relu.  Tin in, bf16 out, NCHW.
// Block: 256 threads -> 16x16 spatial tile x all 64 output channels.
// Thread: 8 output channels x (1 row x 8 cols).  fp32 accumulate.
// ---------------------------------------------------------------------------
template <typename Tin>
__global__ __launch_bounds__(256) void conv3x3_c64_relu(
    const Tin* __restrict__ in,     // [batch][64][H][W]
    bf16* __restrict__ out,         // [batch][64][H][W]
    const float* __restrict__ wt,   // [64][64][3][3]
    const float* __restrict__ bias, // [64]
    int H, int W)
{
    __shared__ float s_in[18 * 18];   // input patch (tile + 1 halo), one cin
    __shared__ float s_w[9 * 64];     // weights for one cin: [tap][cout]

    const int b   = blockIdx.z;
    const int tx0 = blockIdx.x * 16;
    const int ty0 = blockIdx.y * 16;
    const int tid = threadIdx.x;

    const int g      = tid & 31;         // 32 threads cover 16x16 px (8 px each)
    const int cobase = (tid >> 5) << 3;  // 8 groups x 8 cout
    const int r      = g >> 1;           // row 0..15
    const int cx     = (g & 1) << 3;     // col 0 or 8

    const long chan_sz = (long)H * W;
    const long inoff   = (long)b * 64 * chan_sz;

    float acc[8][8];
#pragma unroll
    for (int i = 0; i < 8; ++i)
#pragma unroll
        for (int j = 0; j < 8; ++j) acc[i][j] = 0.f;

    for (int ci = 0; ci < 64; ++ci) {
        __syncthreads();   // protect LDS from previous iteration's readers
        const Tin* ch = in + inoff + ci * chan_sz;
        // stage 18x18 input patch (zero-padded SAME borders)
        for (int idx = tid; idx < 324; idx += 256) {
            int py = ty0 - 1 + idx / 18;
            int px = tx0 - 1 + idx % 18;
            float v = 0.f;
            if (py >= 0 && py < H && px >= 0 && px < W) v = (float)ch[(long)py * W + px];
            s_in[idx] = v;
        }
        // stage weights for this cin: s_w[tap*64 + co]
#pragma unroll
        for (int k = 0; k < 3; ++k) {
            int id2 = tid + k * 256;
            if (id2 < 576) {
                int co = id2 & 63, tap = id2 >> 6;
                s_w[tap * 64 + co] = wt[(co * 64 + ci) * 9 + tap];
            }
        }
        __syncthreads();

        float pin[3][10];
#pragma unroll
        for (int dy = 0; dy < 3; ++dy)
#pragma unroll
            for (int dx = 0; dx < 10; ++dx)
                pin[dy][dx] = s_in[(r + dy) * 18 + cx + dx];

#pragma unroll
        for (int tap = 0; tap < 9; ++tap) {
            const float4 w0 = *(const float4*)&s_w[tap * 64 + cobase];
            const float4 w1 = *(const float4*)&s_w[tap * 64 + cobase + 4];
            const float wv[8] = {w0.x, w0.y, w0.z, w0.w, w1.x, w1.y, w1.z, w1.w};
            const int dy = tap / 3, dx = tap % 3;
#pragma unroll
            for (int co = 0; co < 8; ++co)
#pragma unroll
                for (int px = 0; px < 8; ++px)
                    acc[co][px] += pin[dy][px + dx] * wv[co];
        }
    }

    const int oy = ty0 + r;
#pragma unroll
    for (int co = 0; co < 8; ++co) {
        float bv = bias[cobase + co];
        bf16* op = out + inoff + ((long)(cobase + co) * H + oy) * W + tx0 + cx;
#pragma unroll
        for (int px = 0; px < 8; ++px) {
            float v = acc[co][px] + bv;
            v = v > 0.f ? v : 0.f;
            op[px] = (bf16)v;
        }
    }
}

// ---------------------------------------------------------------------------
// conv 3x3 SAME, Cin=64, Cout=1, + bias + relu.  bf16 in, fp32 out.
// Block: 256 threads = 16x16 tile, 1 output/thread.
// ---------------------------------------------------------------------------
__global__ __launch_bounds__(256) void conv3x3_c1_relu(
    const bf16* __restrict__ in,    // [batch][64][H][W]
    float* __restrict__ out,        // [batch][H][W]
    const float* __restrict__ wt,   // [1][64][3][3]
    const float* __restrict__ bias, // [1]
    int H, int W)
{
    __shared__ float s_in[18 * 18];
    __shared__ float s_w[64 * 9];

    const int b   = blockIdx.z;
    const int tx0 = blockIdx.x * 16;
    const int ty0 = blockIdx.y * 16;
    const int tid = threadIdx.x;

    for (int k = tid; k < 576; k += 256) s_w[k] = wt[k];

    const int px = tid & 15, py = tid >> 4;
    const long chan_sz = (long)H * W;
    const long inoff   = (long)b * 64 * chan_sz;
    float acc = 0.f;

    for (int ci = 0; ci < 64; ++ci) {
        __syncthreads();
        const bf16* ch = in + inoff + ci * chan_sz;
        for (int idx = tid; idx < 324; idx += 256) {
            int iy = ty0 - 1 + idx / 18;
            int ix = tx0 - 1 + idx % 18;
            float v = 0.f;
            if (iy >= 0 && iy < H && ix >= 0 && ix < W) v = (float)ch[(long)iy * W + ix];
            s_in[idx] = v;
        }
        __syncthreads();
#pragma unroll
        for (int tap = 0; tap < 9; ++tap) {
            const int dy = tap / 3, dx = tap % 3;
            acc += s_in[(py + dy) * 18 + px + dx] * s_w[ci * 9 + tap];
        }
    }
    float v = acc + bias[0];
    v = v > 0.f ? v : 0.f;
    out[(long)b * chan_sz + (long)(ty0 + py) * W + tx0 + px] = v;
}

// ---------------------------------------------------------------------------
// Fused: per-pixel bilinear sample of 8 instance masks, softmax over 9 logits
// (bg gets +BIG outside box coverage), then blend 64 channels of bilinearly
// upsampled instance features + bg feature.
// Grid: (2, 512), block 256 -> thread = one pixel, loops 64 channels.
// ---------------------------------------------------------------------------
__global__ __launch_bounds__(256) void fuse_out(
    const float* __restrict__ inst, // [8][64][128][128]
    const float* __restrict__ bg,   // [64][512][512]
    const float* __restrict__ m,    // [8][128][128]  (instance pred masks)
    const float* __restrict__ bgm,  // [512][512]     (bg pred mask)
    float* __restrict__ out)        // [64][512][512]
{
    const int x = blockIdx.x * 256 + threadIdx.x;
    const int y = blockIdx.y;

    // BOX_INFO: l, t, bw, bh   (compile-time constants)
    constexpr int BL[8]  = {0, 64, 128, 300, 64, 200, 32, 256};
    constexpr int BT[8]  = {0, 32, 256, 300, 128, 100, 256, 320};
    constexpr int BBW[8] = {256, 192, 320, 128, 384, 256, 160, 224};
    constexpr int BBH[8] = {256, 320, 192, 128, 256, 384, 224, 160};

    float logits[9];
    bool  ins[8];
    int   o00[8], o01[8], o10[8], o11[8];  // offsets within a 128x128 channel
    float wf00[8], wf01[8], wf10[8], wf11[8];
    bool any = false;

#pragma unroll
    for (int n = 0; n < 8; ++n) {
        const bool inside = (x >= BL[n]) && (x < BL[n] + BBW[n]) &&
                            (y >= BT[n]) && (y < BT[n] + BBH[n]);
        ins[n] = inside;
        float lg = 0.f;
        o00[n] = o01[n] = o10[n] = o11[n] = 0;
        wf00[n] = wf01[n] = wf10[n] = wf11[n] = 0.f;
        if (inside) {
            any = true;
            float u = ((x - BL[n]) + 0.5f) * (128.0f / BBW[n]) - 0.5f;
            float v = ((y - BT[n]) + 0.5f) * (128.0f / BBH[n]) - 0.5f;
            u = fminf(fmaxf(u, 0.f), 127.f);
            v = fminf(fmaxf(v, 0.f), 127.f);
            int   x0 = (int)u;  float fx = u - (float)x0;  int x1 = min(x0 + 1, 127);
            int   y0 = (int)v;  float fy = v - (float)y0;  int y1 = min(y0 + 1, 127);
            o00[n] = y0 * 128 + x0;  o01[n] = y0 * 128 + x1;
            o10[n] = y1 * 128 + x0;  o11[n] = y1 * 128 + x1;
            wf00[n] = (1.f - fx) * (1.f - fy);
            wf01[n] = fx * (1.f - fy);
            wf10[n] = (1.f - fx) * fy;
            wf11[n] = fx * fy;
            const float* mp = m + n * 16384;
            lg = wf00[n] * mp[o00[n]] + wf01[n] * mp[o01[n]] +
                 wf10[n] * mp[o10[n]] + wf11[n] * mp[o11[n]];
        }
        logits[n] = lg;
    }
    logits[8] = bgm[y * 512 + x] + (any ? 0.f : BIG);

    float mx = logits[0];
#pragma unroll
    for (int i = 1; i < 9; ++i) mx = fmaxf(mx, logits[i]);
    float wgt[9], s = 0.f;
#pragma unroll
    for (int i = 0; i < 9; ++i) { wgt[i] = __expf(logits[i] - mx); s += wgt[i]; }
    const float inv = 1.f / s;
#pragma unroll
    for (int i = 0; i < 9; ++i) wgt[i] *= inv;

    // fold softmax weight into the 4 bilinear taps
#pragma unroll
    for (int n = 0; n < 8; ++n) {
        wf00[n] *= wgt[n]; wf01[n] *= wgt[n];
        wf10[n] *= wgt[n]; wf11[n] *= wgt[n];
    }

    const long pix = (long)y * 512 + x;
    for (int c = 0; c < 64; ++c) {
        float o = wgt[8] * bg[(long)c * 262144 + pix];
#pragma unroll
        for (int n = 0; n < 8; ++n) {
            if (ins[n]) {
                const float* p = inst + (long)(n * 64 + c) * 16384;
                o += wf00[n] * p[o00[n]] + wf01[n] * p[o01[n]] +
                     wf10[n] * p[o10[n]] + wf11[n] * p[o11[n]];
            }
        }
        out[(long)c * 262144 + pix] = o;
    }
}

// ---------------------------------------------------------------------------
extern "C" void kernel_launch(void* const* d_in, const int* in_sizes, int n_in,
                              void* d_out, int out_size, void* d_ws, size_t ws_size,
                              hipStream_t stream)
{
    (void)in_sizes; (void)n_in; (void)out_size; (void)ws_size;

    const float* instf = (const float*)d_in[0];   // 8x64x128x128
    const float* bgf   = (const float*)d_in[1];   // 1x64x512x512
    const float* iw1   = (const float*)d_in[2];
    const float* ib1   = (const float*)d_in[3];
    const float* iw2   = (const float*)d_in[4];
    const float* ib2   = (const float*)d_in[5];
    const float* iw3   = (const float*)d_in[6];
    const float* ib3   = (const float*)d_in[7];
    const float* bw1   = (const float*)d_in[8];
    const float* bb1   = (const float*)d_in[9];
    const float* bw2   = (const float*)d_in[10];
    const float* bb2   = (const float*)d_in[11];
    const float* bw3   = (const float*)d_in[12];
    const float* bb3   = (const float*)d_in[13];

    // workspace layout (68,681,728 B total):
    //   region A [0 .. 33.5MB):  y1 (16.7MB bf16) + y2 (16.7MB bf16);
    //                            later reused as bg1 (33.5MB bf16)
    //   region B [33.5 .. 67.1MB): bg2 (bf16)
    //   m_inst  f32 @67,108,864 (0.5MB) ; bg_mask f32 @67,633,152 (1MB)
    char* ws = (char*)d_ws;
    bf16*  y1     = (bf16*)(ws);
    bf16*  y2     = (bf16*)(ws + 16777216);
    bf16*  bg1    = (bf16*)(ws);              // reuse A after instance convs done
    bf16*  bg2    = (bf16*)(ws + 33554432);
    float* minst  = (float*)(ws + 67108864);  // 8x128x128 f32
    float* bgmask = (float*)(ws + 67633152);  // 512x512 f32

    // instance block (batch=8, 128x128)
    conv3x3_c64_relu<float><<<dim3(8, 8, 8), 256, 0, stream>>>(instf, y1, iw1, ib1, 128, 128);
    conv3x3_c64_relu<bf16> <<<dim3(8, 8, 8), 256, 0, stream>>>(y1, y2, iw2, ib2, 128, 128);
    conv3x3_c1_relu        <<<dim3(8, 8, 8), 256, 0, stream>>>(y2, minst, iw3, ib3, 128, 128);

    // bg block (batch=1, 512x512)
    conv3x3_c64_relu<float><<<dim3(32, 32, 1), 256, 0, stream>>>(bgf, bg1, bw1, bb1, 512, 512);
    conv3x3_c64_relu<bf16> <<<dim3(32, 32, 1), 256, 0, stream>>>(bg1, bg2, bw2, bb2, 512, 512);
    conv3x3_c1_relu        <<<dim3(32, 32, 1), 256, 0, stream>>>(bg2, bgmask, bw3, bb3, 512, 512);

    // fused resize + softmax + blend
    fuse_out<<<dim3(2, 512), 256, 0, stream>>>(instf, bgf, minst, bgmask, (float*)d_out);
}

// Round 5
// 512.866 us; speedup vs baseline: 2.7781x; 2.7781x over previous
//
#include <hip/hip_runtime.h>
#include <hip/hip_bf16.h>

typedef __hip_bfloat16 bf16;
typedef unsigned short ushort_t;
typedef unsigned int uint32;

typedef short short4_t __attribute__((ext_vector_type(4)));
typedef short short8_t __attribute__((ext_vector_type(8)));
typedef float float4_t __attribute__((ext_vector_type(4)));

union FragU { short4_t h[2]; short8_t v; };
union Frag16 { short8_t v; short s[8]; uint4 u; };

#define BIG 100000.0f

// ---------------------------------------------------------------------------
// weights [64co][64ci][3][3] f32  ->  [9tap][64co][64ci] bf16 bits
// ---------------------------------------------------------------------------
__global__ __launch_bounds__(256) void wtrans(const float* __restrict__ w,
                                              ushort_t* __restrict__ dst)
{
    int idx = blockIdx.x * 256 + threadIdx.x;  // 36864 total
    if (idx < 36864) {
        int ci = idx & 63, co = (idx >> 6) & 63, t = idx >> 12;
        bf16 h = (bf16)w[(co * 64 + ci) * 9 + t];
        dst[idx] = *(ushort_t*)&h;
    }
}

// ---------------------------------------------------------------------------
// NCHW f32 -> NHWC bf16 (C=64).  Block: one row-y, 64 x.  LDS transpose.
// ---------------------------------------------------------------------------
__global__ __launch_bounds__(256) void nchw_to_nhwc(
    const float* __restrict__ in,   // [B][64][H][W]
    ushort_t* __restrict__ out,     // [B][H][W][64]
    int H, int W)
{
    __shared__ ushort_t s[64 * 66];
    const int b = blockIdx.z, y = blockIdx.y, x0 = blockIdx.x * 64;
    const int tid = threadIdx.x;
    const long ibase = (long)b * 64 * H * W + (long)y * W + x0;
    {
        const int x = tid & 63, dc = tid >> 6;
        for (int c = dc; c < 64; c += 4) {
            bf16 h = (bf16)in[ibase + (long)c * H * W + x];
            s[c * 66 + x] = *(ushort_t*)&h;
        }
    }
    __syncthreads();
    {
        const int c = tid & 63, dx = tid >> 6;
        const long obase = ((long)b * H * W + (long)y * W + x0) * 64;
        for (int x = dx; x < 64; x += 4)
            out[obase + (long)x * 64 + c] = s[c * 66 + x];
    }
}

// ---------------------------------------------------------------------------
// conv 3x3 SAME, 64->64 + bias + relu, NHWC bf16, MFMA 16x16x32.
// WG 256 thr / 4 waves: 16x16 px tile x 64 cout.  Wave = 4 rows x 64 cout
// (4 m-blocks x 4 n-blocks).  K = cin, split in 2 halves of 32; 9 taps.
// LDS: input patch 18x18 px x 32ci (stride 36) + weights 9x64co x 32ci.
// ---------------------------------------------------------------------------
__global__ __launch_bounds__(256) void conv3x3_mfma(
    const ushort_t* __restrict__ in,   // [B][H][W][64] bf16
    ushort_t* __restrict__ out,        // [B][H][W][64] bf16
    const ushort_t* __restrict__ wt,   // [9][64][64] bf16
    const float* __restrict__ bias,    // [64] f32
    int H, int W)
{
    __shared__ ushort_t s_in[324 * 36];     // 23,328 B
    __shared__ ushort_t s_w[9 * 64 * 36];   // 41,472 B  (total 64,800 <= 64K)

    const int b = blockIdx.z;
    const int x0 = blockIdx.x * 16, y0 = blockIdx.y * 16;
    const int tid = threadIdx.x;
    const int lane = tid & 63, wv = tid >> 6;
    const int n = lane & 15, q = lane >> 4;   // n: M or N index, q: k-quad

    const long img = (long)b * H * W;

    float4_t acc[4][4];
#pragma unroll
    for (int mb = 0; mb < 4; ++mb)
#pragma unroll
        for (int j = 0; j < 4; ++j) acc[mb][j] = (float4_t){0.f, 0.f, 0.f, 0.f};

    for (int half = 0; half < 2; ++half) {
        __syncthreads();
        // ---- stage input patch: 324 px x 32 ci = 324*4 = 1296 chunks of 8
        for (int idx = tid; idx < 1296; idx += 256) {
            const int p = idx >> 2, c = idx & 3;
            const int py = p / 18, px = p - py * 18;
            const int gy = y0 - 1 + py, gx = x0 - 1 + px;
            uint4 d = {0u, 0u, 0u, 0u};
            if (gy >= 0 && gy < H && gx >= 0 && gx < W)
                d = *(const uint4*)(in + ((img + (long)gy * W + gx) << 6) + half * 32 + c * 8);
            ushort_t* dp = &s_in[p * 36 + c * 8];
            *(uint2*)dp       = make_uint2(d.x, d.y);
            *(uint2*)(dp + 4) = make_uint2(d.z, d.w);
        }
        // ---- stage weights: 9*64 = 576 rows x 32 ci = 576*4 = 2304 chunks
        // (was 1152: only half the taps staged -> garbage -> NaN)
        for (int idx = tid; idx < 2304; idx += 256) {
            const int wc = idx >> 2, c = idx & 3;  // wc = t*64+co in [0,576)
            const uint4 d = *(const uint4*)(wt + (wc << 6) + half * 32 + c * 8);
            ushort_t* dp = &s_w[wc * 36 + c * 8];
            *(uint2*)dp       = make_uint2(d.x, d.y);
            *(uint2*)(dp + 4) = make_uint2(d.z, d.w);
        }
        __syncthreads();

#pragma unroll
        for (int t = 0; t < 9; ++t) {
            const int dy = t / 3, dx = t - dy * 3;
            FragU A[4];
#pragma unroll
            for (int mb = 0; mb < 4; ++mb) {
                const ushort_t* p = &s_w[(t * 64 + mb * 16 + n) * 36 + q * 8];
                A[mb].h[0] = *(const short4_t*)p;
                A[mb].h[1] = *(const short4_t*)(p + 4);
            }
#pragma unroll
            for (int j = 0; j < 4; ++j) {
                const int row = wv * 4 + j;
                const ushort_t* p = &s_in[((row + dy) * 18 + n + dx) * 36 + q * 8];
                FragU B;
                B.h[0] = *(const short4_t*)p;
                B.h[1] = *(const short4_t*)(p + 4);
#pragma unroll
                for (int mb = 0; mb < 4; ++mb)
                    acc[mb][j] = __builtin_amdgcn_mfma_f32_16x16x32_bf16(
                        A[mb].v, B.v, acc[mb][j], 0, 0, 0);
            }
        }
    }

    // ---- epilogue: D[m=co][n=px]: co = mb*16 + q*4 + r, px-col = n
#pragma unroll
    for (int mb = 0; mb < 4; ++mb) {
        const int co = mb * 16 + q * 4;
        const float4 bv = *(const float4*)(bias + co);
        const float bvr[4] = {bv.x, bv.y, bv.z, bv.w};
#pragma unroll
        for (int j = 0; j < 4; ++j) {
            const int gy = y0 + wv * 4 + j, gx = x0 + n;
            ushort_t* op = out + ((img + (long)gy * W + gx) << 6) + co;
            bf16 tmp[4];
#pragma unroll
            for (int r = 0; r < 4; ++r) {
                float v = acc[mb][j][r] + bvr[r];
                v = v > 0.f ? v : 0.f;
                tmp[r] = (bf16)v;
            }
            *(uint2*)op = *(uint2*)tmp;
        }
    }
}

// ---------------------------------------------------------------------------
// conv 3x3 SAME, 64->1 + bias + relu.  NHWC bf16 in, f32 out.
// Block 256 = 16x16 px tile, LDS-staged patch (stride 72 -> 16B aligned).
// ---------------------------------------------------------------------------
__global__ __launch_bounds__(256) void conv3x3_c1(
    const ushort_t* __restrict__ in,  // [B][H][W][64] bf16
    float* __restrict__ out,          // [B][H][W]
    const float* __restrict__ w,      // [64][9]  (orig [1][64][3][3])
    const float* __restrict__ bias,   // [1]
    int H, int W)
{
    __shared__ ushort_t s_in[324 * 72];  // 46,656 B
    __shared__ float s_w[576];

    const int b = blockIdx.z;
    const int x0 = blockIdx.x * 16, y0 = blockIdx.y * 16;
    const int tid = threadIdx.x;
    for (int k = tid; k < 576; k += 256) s_w[k] = w[k];

    const long img = (long)b * H * W;
    for (int idx = tid; idx < 2592; idx += 256) {
        const int p = idx >> 3, c = idx & 7;
        const int py = p / 18, px = p - py * 18;
        const int gy = y0 - 1 + py, gx = x0 - 1 + px;
        uint4 d = {0u, 0u, 0u, 0u};
        if (gy >= 0 && gy < H && gx >= 0 && gx < W)
            d = *(const uint4*)(in + ((img + (long)gy * W + gx) << 6) + c * 8);
        *(uint4*)&s_in[p * 72 + c * 8] = d;
    }
    __syncthreads();

    const int px = tid & 15, py = tid >> 4;
    float acc = 0.f;
#pragma unroll
    for (int t = 0; t < 9; ++t) {
        const int dy = t / 3, dx = t - dy * 3;
        const ushort_t* p = &s_in[((py + dy) * 18 + px + dx) * 72];
#pragma unroll
        for (int c8 = 0; c8 < 8; ++c8) {
            Frag16 f;
            f.u = *(const uint4*)(p + c8 * 8);
#pragma unroll
            for (int i = 0; i < 8; ++i) {
                float fv = __uint_as_float(((uint32)(ushort_t)f.s[i]) << 16);
                acc += fv * s_w[(c8 * 8 + i) * 9 + t];
            }
        }
    }
    float v = acc + bias[0];
    v = v > 0.f ? v : 0.f;
    out[img + (long)(y0 + py) * W + x0 + px] = v;
}

// ---------------------------------------------------------------------------
// Fused: bilinear sample of 8 instance masks, softmax over 9 logits
// (bg +BIG outside coverage), blend 64 ch of upsampled inst + bg features.
// ---------------------------------------------------------------------------
__global__ __launch_bounds__(256) void fuse_out(
    const float* __restrict__ inst, // [8][64][128][128]
    const float* __restrict__ bg,   // [64][512][512]
    const float* __restrict__ m,    // [8][128][128]
    const float* __restrict__ bgm,  // [512][512]
    float* __restrict__ out)        // [64][512][512]
{
    const int x = blockIdx.x * 256 + threadIdx.x;
    const int y = blockIdx.y;

    constexpr int BL[8]  = {0, 64, 128, 300, 64, 200, 32, 256};
    constexpr int BT[8]  = {0, 32, 256, 300, 128, 100, 256, 320};
    constexpr int BBW[8] = {256, 192, 320, 128, 384, 256, 160, 224};
    constexpr int BBH[8] = {256, 320, 192, 128, 256, 384, 224, 160};

    float logits[9];
    bool  ins[8];
    int   o00[8], o01[8], o10[8], o11[8];
    float wf00[8], wf01[8], wf10[8], wf11[8];
    bool any = false;

#pragma unroll
    for (int n = 0; n < 8; ++n) {
        const bool inside = (x >= BL[n]) && (x < BL[n] + BBW[n]) &&
                            (y >= BT[n]) && (y < BT[n] + BBH[n]);
        ins[n] = inside;
        float lg = 0.f;
        o00[n] = o01[n] = o10[n] = o11[n] = 0;
        wf00[n] = wf01[n] = wf10[n] = wf11[n] = 0.f;
        if (inside) {
            any = true;
            float u = ((x - BL[n]) + 0.5f) * (128.0f / BBW[n]) - 0.5f;
            float v = ((y - BT[n]) + 0.5f) * (128.0f / BBH[n]) - 0.5f;
            u = fminf(fmaxf(u, 0.f), 127.f);
            v = fminf(fmaxf(v, 0.f), 127.f);
            int   xx0 = (int)u;  float fx = u - (float)xx0;  int xx1 = min(xx0 + 1, 127);
            int   yy0 = (int)v;  float fy = v - (float)yy0;  int yy1 = min(yy0 + 1, 127);
            o00[n] = yy0 * 128 + xx0;  o01[n] = yy0 * 128 + xx1;
            o10[n] = yy1 * 128 + xx0;  o11[n] = yy1 * 128 + xx1;
            wf00[n] = (1.f - fx) * (1.f - fy);
            wf01[n] = fx * (1.f - fy);
            wf10[n] = (1.f - fx) * fy;
            wf11[n] = fx * fy;
            const float* mp = m + n * 16384;
            lg = wf00[n] * mp[o00[n]] + wf01[n] * mp[o01[n]] +
                 wf10[n] * mp[o10[n]] + wf11[n] * mp[o11[n]];
        }
        logits[n] = lg;
    }
    logits[8] = bgm[y * 512 + x] + (any ? 0.f : BIG);

    float mx = logits[0];
#pragma unroll
    for (int i = 1; i < 9; ++i) mx = fmaxf(mx, logits[i]);
    float wgt[9], s = 0.f;
#pragma unroll
    for (int i = 0; i < 9; ++i) { wgt[i] = __expf(logits[i] - mx); s += wgt[i]; }
    const float inv = 1.f / s;
#pragma unroll
    for (int i = 0; i < 9; ++i) wgt[i] *= inv;

#pragma unroll
    for (int n = 0; n < 8; ++n) {
        wf00[n] *= wgt[n]; wf01[n] *= wgt[n];
        wf10[n] *= wgt[n]; wf11[n] *= wgt[n];
    }

    const long pix = (long)y * 512 + x;
    for (int c = 0; c < 64; ++c) {
        float o = wgt[8] * bg[(long)c * 262144 + pix];
#pragma unroll
        for (int n = 0; n < 8; ++n) {
            if (ins[n]) {
                const float* p = inst + (long)(n * 64 + c) * 16384;
                o += wf00[n] * p[o00[n]] + wf01[n] * p[o01[n]] +
                     wf10[n] * p[o10[n]] + wf11[n] * p[o11[n]];
            }
        }
        out[(long)c * 262144 + pix] = o;
    }
}

// ---------------------------------------------------------------------------
extern "C" void kernel_launch(void* const* d_in, const int* in_sizes, int n_in,
                              void* d_out, int out_size, void* d_ws, size_t ws_size,
                              hipStream_t stream)
{
    (void)in_sizes; (void)n_in; (void)out_size; (void)ws_size;

    const float* instf = (const float*)d_in[0];   // 8x64x128x128
    const float* bgf   = (const float*)d_in[1];   // 1x64x512x512
    const float* iw1   = (const float*)d_in[2];
    const float* ib1   = (const float*)d_in[3];
    const float* iw2   = (const float*)d_in[4];
    const float* ib2   = (const float*)d_in[5];
    const float* iw3   = (const float*)d_in[6];
    const float* ib3   = (const float*)d_in[7];
    const float* bw1   = (const float*)d_in[8];
    const float* bb1   = (const float*)d_in[9];
    const float* bw2   = (const float*)d_in[10];
    const float* bb2   = (const float*)d_in[11];
    const float* bw3   = (const float*)d_in[12];
    const float* bb3   = (const float*)d_in[13];

    // workspace layout (68,681,728 B):
    //   R1 [0, 33.55M):  instN(16.78M)+y2(16.78M) -> bgN -> bg2
    //   R2 [33.55M, 67.1M): y1(16.78M) -> bg1(33.55M)
    //   minst f32 @67,108,864 (0.5M)
    //   bgmask f32 @67,633,152 (1M)   [wt bf16 aliased here: dead before
    //                                  bgmask is written at bg layer-3]
    char* ws = (char*)d_ws;
    ushort_t* instN = (ushort_t*)(ws);                  // 8x128x128x64 bf16
    ushort_t* y2    = (ushort_t*)(ws + 16777216);
    ushort_t* y1    = (ushort_t*)(ws + 33554432);
    ushort_t* bgN   = (ushort_t*)(ws);                  // 512x512x64 bf16
    ushort_t* bg1   = (ushort_t*)(ws + 33554432);
    ushort_t* bg2   = (ushort_t*)(ws);
    float*    minst  = (float*)(ws + 67108864);
    float*    bgmask = (float*)(ws + 67633152);
    ushort_t* wt0 = (ushort_t*)(ws + 67633152);         // aliased w/ bgmask
    ushort_t* wt1 = wt0 + 36864;
    ushort_t* wt2 = wt0 + 2 * 36864;
    ushort_t* wt3 = wt0 + 3 * 36864;

    // weight transforms
    wtrans<<<144, 256, 0, stream>>>(iw1, wt0);
    wtrans<<<144, 256, 0, stream>>>(iw2, wt1);
    wtrans<<<144, 256, 0, stream>>>(bw1, wt2);
    wtrans<<<144, 256, 0, stream>>>(bw2, wt3);

    // instance pipeline (8x 128x128)
    nchw_to_nhwc<<<dim3(2, 128, 8), 256, 0, stream>>>(instf, instN, 128, 128);
    conv3x3_mfma<<<dim3(8, 8, 8), 256, 0, stream>>>(instN, y1, wt0, ib1, 128, 128);
    conv3x3_mfma<<<dim3(8, 8, 8), 256, 0, stream>>>(y1, y2, wt1, ib2, 128, 128);
    conv3x3_c1  <<<dim3(8, 8, 8), 256, 0, stream>>>(y2, minst, iw3, ib3, 128, 128);

    // bg pipeline (512x512)
    nchw_to_nhwc<<<dim3(8, 512, 1), 256, 0, stream>>>(bgf, bgN, 512, 512);
    conv3x3_mfma<<<dim3(32, 32, 1), 256, 0, stream>>>(bgN, bg1, wt2, bb1, 512, 512);
    conv3x3_mfma<<<dim3(32, 32, 1), 256, 0, stream>>>(bg1, bg2, wt3, bb2, 512, 512);
    conv3x3_c1  <<<dim3(32, 32, 1), 256, 0, stream>>>(bg2, bgmask, bw3, bb3, 512, 512);

    // fused resize + softmax + blend
    fuse_out<<<dim3(2, 512), 256, 0, stream>>>(instf, bgf, minst, bgmask, (float*)d_out);
}